// Round 9
// baseline (274.280 us; speedup 1.0000x reference)
//
#include <hip/hip_runtime.h>

// k-means cluster step: N=400000, D=256, K=50 (fp32 in/out).
// Round 9: both passes rebuilt as ring-3 streaming pipelines with COUNTED
// vmcnt (T3/T4: never drain to 0 in-loop) + raw s_barrier, replacing the
// 2-deep __syncthreads pipelines that stalled at ~3.4 TB/s.
//   k_assign : scores=X*C^T (mfma 16x16x32 f16). 8 waves = (pt2 x clp2 x kh2),
//              K split across kh -> A-frags read 2x not 4x; kh-partials
//              combined via 8KB LDS; argmin + idx store + LDS counts.
//   k_scatter: sums = onehot(idx)^T * X. 16 waves = 16 n-tiles, each wave
//              all 4 m-tiles -> col-reads cut 4x (128 b32/chunk, 2-way-free).
//              idx prefetched 1 chunk ahead as 2 pinned int4 loads.
//   k_reduce : partial reduction (atomicAdd, out pre-zeroed by memset).

typedef _Float16 f16x8 __attribute__((ext_vector_type(8)));
typedef float    f32x4 __attribute__((ext_vector_type(4)));
typedef int      i32x4 __attribute__((ext_vector_type(4)));

constexpr int K = 50, KP = 64, D = 256, KD = K * D;
constexpr int A_BLK = 512,  A_GRID = 256;
constexpr int S_BLK = 1024, S_GRID = 256;
constexpr int CH = 32;   // points per chunk (N % 32 == 0 for this problem)

#define AS_GLB(p) (const __attribute__((address_space(1))) void*)(p)
#define AS_LDS(p) (__attribute__((address_space(3))) void*)(p)
#define VMCNT_(n) asm volatile("s_waitcnt vmcnt(" #n ")" ::: "memory")
#define LGKM0     asm volatile("s_waitcnt lgkmcnt(0)" ::: "memory")
#define SBAR      { __builtin_amdgcn_sched_barrier(0); __builtin_amdgcn_s_barrier(); __builtin_amdgcn_sched_barrier(0); }

// ---------------------------------------------------------------- assign ---
__global__ __launch_bounds__(A_BLK)
void k_assign(const float* __restrict__ x, const float* __restrict__ cc,
              int* __restrict__ idxg, float* __restrict__ out, int N) {
    __shared__ _Float16 sC[KP * D];          // 32KB, chunk-XOR swizzle ^(r&7)
    __shared__ float    sc2[KP];
    __shared__ float    sx[3][CH * D];       // 96KB ring-3 staging
    __shared__ f32x4    sacc[2][2][2][64];   // 8KB [pt][clp][cl2][lane]
    __shared__ float    sredm[2][CH];
    __shared__ int      sredb[2][CH];
    __shared__ int      scnt[K];

    const int tid = threadIdx.x;
    for (int i = tid; i < KP * D; i += A_BLK) sC[i] = (_Float16)0.f;
    if (tid < K) scnt[tid] = 0;
    __syncthreads();
    for (int i = tid; i < KD; i += A_BLK) {
        int r = i >> 8, col = i & 255, ch = col >> 3, wd = col & 7;
        sC[r * D + (((ch ^ (r & 7)) << 3) | wd)] = (_Float16)cc[i];
    }
    if (tid < KP) {
        float s = 0.f;
        if (tid < K) for (int q = 0; q < D; ++q) { float v = cc[tid * D + q]; s += v * v; }
        sc2[tid] = s;
    }
    __syncthreads();

    const int lane = tid & 63, ci = lane & 15, g = lane >> 4, w = tid >> 6;
    const int pt = w & 1, clp = (w >> 1) & 1, kh = w >> 2;
    const int akey = ci & 7;                 // = row&7 for both x rows and sC rows
    const int arow = pt * 16 + ci;
    const int cr0 = clp * 32 + ci, cr1 = cr0 + 16;

    const float INF = 3.4e38f;
    const float c2a = (cr0 < K) ? sc2[cr0] : INF;
    const float c2b = (cr1 < K) ? sc2[cr1] : INF;

    const int nCh = N / CH;
    const int cpb = nCh / gridDim.x, rem = nCh % gridDim.x;
    const int bid = blockIdx.x;
    const int lo  = bid * cpb + (bid < rem ? bid : rem);
    const int cnt = cpb + (bid < rem ? 1 : 0);

    // wave w stages rows 4w..4w+3; src pre-swizzled in 16B chunks ^(row&7)
#define A_STAGE(s_, t_) { \
    const float* base_ = x + (size_t)(t_) * (CH * D); \
    _Pragma("unroll") \
    for (int r4 = 0; r4 < 4; ++r4) { \
        const int row_ = 4 * w + r4; \
        const float* src_ = base_ + row_ * D + ((lane ^ (row_ & 7)) << 2); \
        __builtin_amdgcn_global_load_lds(AS_GLB(src_), AS_LDS(&sx[s_][row_ * D]), 16, 0, 0); } }

    if (cnt > 0) A_STAGE(0, lo)
    if (cnt > 1) A_STAGE(1, lo + 1)

    for (int i = 0; i < cnt; ++i) {
        const int t = lo + i;
        // counted vmcnt: guarantee stage(i) landed, keep stage(i+1/i+2) in
        // flight. Per-wave VMEM order: [stage x4, (wave0: idx-store x1)].
        // In-order vmcnt retirement (m135) makes the counts exact.
        if (i + 2 < cnt) {
            A_STAGE((i + 2) % 3, t + 2)
            if (w == 0 && i >= 2) { VMCNT_(10); } else { VMCNT_(8); }
        } else if (i + 1 < cnt) {
            if (w == 0) { VMCNT_(6); } else { VMCNT_(4); }
        } else {
            if (w == 0) { VMCNT_(2); } else { VMCNT_(0); }
        }
        SBAR;

        const float* xb = &sx[i % 3][0];
        f32x4 acc0 = {0,0,0,0}, acc1 = {0,0,0,0};
#define A_KS(S) { \
        const int ks_ = kh * 4 + S; \
        f32x4 u0 = *(const f32x4*)(xb + arow * D + (((ks_ * 8 + 2 * g + 0) ^ akey) << 2)); \
        f32x4 u1 = *(const f32x4*)(xb + arow * D + (((ks_ * 8 + 2 * g + 1) ^ akey) << 2)); \
        f16x8 a = {(_Float16)u0[0], (_Float16)u0[1], (_Float16)u0[2], (_Float16)u0[3], \
                   (_Float16)u1[0], (_Float16)u1[1], (_Float16)u1[2], (_Float16)u1[3]}; \
        { f16x8 b = *(const f16x8*)(&sC[cr0 * D + (((ks_ * 4 + g) ^ akey) << 3)]); \
          acc0 = __builtin_amdgcn_mfma_f32_16x16x32_f16(a, b, acc0, 0, 0, 0); } \
        { f16x8 b = *(const f16x8*)(&sC[cr1 * D + (((ks_ * 4 + g) ^ akey) << 3)]); \
          acc1 = __builtin_amdgcn_mfma_f32_16x16x32_f16(a, b, acc1, 0, 0, 0); } }
        A_KS(0) A_KS(1) A_KS(2) A_KS(3)
#undef A_KS

        if (kh == 1) {
            sacc[pt][clp][0][lane] = acc0;
            sacc[pt][clp][1][lane] = acc1;
        }
        LGKM0; SBAR;
        if (kh == 0) {
            acc0 += sacc[pt][clp][0][lane];
            acc1 += sacc[pt][clp][1][lane];
            // argmin over this wave's 32 clusters; RED16 over ci with
            // first-min (smallest index) tie-break
#define AMIN(r) { \
            float m_ = c2a - 2.f * acc0[r]; int b_ = cr0; \
            { float s_ = c2b - 2.f * acc1[r]; if (s_ < m_) { m_ = s_; b_ = cr1; } } \
            { float pm_; int pb_; \
              pm_ = __shfl_xor(m_, 1, 64); pb_ = __shfl_xor(b_, 1, 64); \
              if (pm_ < m_ || (pm_ == m_ && pb_ < b_)) { m_ = pm_; b_ = pb_; } \
              pm_ = __shfl_xor(m_, 2, 64); pb_ = __shfl_xor(b_, 2, 64); \
              if (pm_ < m_ || (pm_ == m_ && pb_ < b_)) { m_ = pm_; b_ = pb_; } \
              pm_ = __shfl_xor(m_, 4, 64); pb_ = __shfl_xor(b_, 4, 64); \
              if (pm_ < m_ || (pm_ == m_ && pb_ < b_)) { m_ = pm_; b_ = pb_; } \
              pm_ = __shfl_xor(m_, 8, 64); pb_ = __shfl_xor(b_, 8, 64); \
              if (pm_ < m_ || (pm_ == m_ && pb_ < b_)) { m_ = pm_; b_ = pb_; } } \
            if (ci == 0) { sredm[clp][pt * 16 + 4 * g + r] = m_; \
                           sredb[clp][pt * 16 + 4 * g + r] = b_; } }
            AMIN(0) AMIN(1) AMIN(2) AMIN(3)
#undef AMIN
        }
        LGKM0; SBAR;
        if (tid < CH) {
            float m0 = sredm[0][tid], m1 = sredm[1][tid];
            int   b0 = sredb[0][tid], b1 = sredb[1][tid];
            const int best = (m1 < m0) ? b1 : b0;   // tie -> b0 (smaller idx)
            const int p = t * CH + tid;
            if (p < N) { idxg[p] = best; atomicAdd(&scnt[best], 1); }
        }
    }

    __syncthreads();
    for (int k = tid; k < K; k += A_BLK) atomicAdd(&out[KD + k], (float)scnt[k]);
}

// --------------------------------------------------------------- scatter ---
__global__ __launch_bounds__(S_BLK)
void k_scatter(const float* __restrict__ x, const int* __restrict__ idxg,
               float* __restrict__ partial, float* __restrict__ out,
               int N, int useAtomic) {
    __shared__ float sx[3][CH * D];   // 96KB ring-3

    const int tid = threadIdx.x;
    const int lane = tid & 63, ci = lane & 15, g = lane >> 4, w = tid >> 6;
    const int e = ci & 3, c2 = ci >> 2;

    const int nCh = N / CH;
    const int cpb = nCh / gridDim.x, rem = nCh % gridDim.x;
    const int bid = blockIdx.x;
    const int lo  = bid * cpb + (bid < rem ? bid : rem);
    const int cnt = cpb + (bid < rem ? 1 : 0);

    // wave w stages rows 2w, 2w+1; swizzle key ((row>>3)&1)<<2 makes the
    // col-wise B-frag reads 2-way (free)
#define S_STAGE(s_, t_) { \
    const float* base_ = x + (size_t)(t_) * (CH * D); \
    _Pragma("unroll") \
    for (int r2 = 0; r2 < 2; ++r2) { \
        const int row_ = 2 * w + r2; \
        const float* src_ = base_ + row_ * D + ((lane ^ (((row_ >> 3) & 1) << 2)) << 2); \
        __builtin_amdgcn_global_load_lds(AS_GLB(src_), AS_LDS(&sx[s_][row_ * D]), 16, 0, 0); } }

    f32x4 acc0 = {0,0,0,0}, acc1 = {0,0,0,0}, acc2v = {0,0,0,0}, acc3 = {0,0,0,0};
    const int coff = ((w * 4 + c2) ^ ((g & 1) << 2)) * 4 + e;  // swizzled col offset

    i32x4 idA = {0,0,0,0}, idB = {0,0,0,0};
    i32x4 nxA = {0,0,0,0}, nxB = {0,0,0,0};

    if (cnt > 0) {
        S_STAGE(0, lo)
        idA = *(const i32x4*)(idxg + (size_t)lo * CH + 8 * g);
        idB = *(const i32x4*)(idxg + (size_t)lo * CH + 8 * g + 4);
        if (cnt > 1) S_STAGE(1, lo + 1)
    }

    for (int i = 0; i < cnt; ++i) {
        const int t = lo + i;
        if (i + 1 < cnt) {   // prefetch next chunk's idx (2 pinned int4 loads)
            nxA = *(const i32x4*)(idxg + (size_t)(t + 1) * CH + 8 * g);
            nxB = *(const i32x4*)(idxg + (size_t)(t + 1) * CH + 8 * g + 4);
        }
        // per-wave VMEM order/iter: [idx x2, stage x2] -> younger-than-stage(i)
        // = 2+2+2+2 = 8 steady; 6 mid-tail; 2 last.
        if (i + 2 < cnt)      { S_STAGE((i + 2) % 3, t + 2) VMCNT_(8); }
        else if (i + 1 < cnt) { VMCNT_(6); }
        else                  { VMCNT_(2); }
        SBAR;

        const float* xb = &sx[i % 3][0];
        float f0 = xb[(8 * g + 0) * D + coff], f1 = xb[(8 * g + 1) * D + coff];
        float f2 = xb[(8 * g + 2) * D + coff], f3 = xb[(8 * g + 3) * D + coff];
        float f4 = xb[(8 * g + 4) * D + coff], f5 = xb[(8 * g + 5) * D + coff];
        float f6 = xb[(8 * g + 6) * D + coff], f7 = xb[(8 * g + 7) * D + coff];
        f16x8 b = {(_Float16)f0, (_Float16)f1, (_Float16)f2, (_Float16)f3,
                   (_Float16)f4, (_Float16)f5, (_Float16)f6, (_Float16)f7};
#define SMT(M, ACC) { \
        const int cl_ = M * 16 + ci; \
        f16x8 a = {(_Float16)(idA[0] == cl_ ? 1.f : 0.f), (_Float16)(idA[1] == cl_ ? 1.f : 0.f), \
                   (_Float16)(idA[2] == cl_ ? 1.f : 0.f), (_Float16)(idA[3] == cl_ ? 1.f : 0.f), \
                   (_Float16)(idB[0] == cl_ ? 1.f : 0.f), (_Float16)(idB[1] == cl_ ? 1.f : 0.f), \
                   (_Float16)(idB[2] == cl_ ? 1.f : 0.f), (_Float16)(idB[3] == cl_ ? 1.f : 0.f)}; \
        ACC = __builtin_amdgcn_mfma_f32_16x16x32_f16(a, b, ACC, 0, 0, 0); }
        SMT(0, acc0) SMT(1, acc1) SMT(2, acc2v) SMT(3, acc3)
#undef SMT
        SBAR;   // all waves done reading sx[i%3] before it is re-staged
        idA = nxA; idB = nxB;
    }

    // D layout: row(cluster) = M*16 + 4g + r, col = w*16 + ci
    const int col = w * 16 + ci;
#define WB(M, ACC) { \
    { int cl_ = M * 16 + 4 * g + 0; if (cl_ < K) { if (useAtomic) atomicAdd(&out[cl_ * D + col], ACC[0]); else partial[(size_t)bid * KD + cl_ * D + col] = ACC[0]; } } \
    { int cl_ = M * 16 + 4 * g + 1; if (cl_ < K) { if (useAtomic) atomicAdd(&out[cl_ * D + col], ACC[1]); else partial[(size_t)bid * KD + cl_ * D + col] = ACC[1]; } } \
    { int cl_ = M * 16 + 4 * g + 2; if (cl_ < K) { if (useAtomic) atomicAdd(&out[cl_ * D + col], ACC[2]); else partial[(size_t)bid * KD + cl_ * D + col] = ACC[2]; } } \
    { int cl_ = M * 16 + 4 * g + 3; if (cl_ < K) { if (useAtomic) atomicAdd(&out[cl_ * D + col], ACC[3]); else partial[(size_t)bid * KD + cl_ * D + col] = ACC[3]; } } }
    WB(0, acc0) WB(1, acc1) WB(2, acc2v) WB(3, acc3)
#undef WB
}

// ---------------------------------------------------------------- reduce ---
__global__ __launch_bounds__(256)
void k_reduce(const float* __restrict__ partial, float* __restrict__ out, int G) {
    const int j  = blockIdx.x * 256 + threadIdx.x;    // < KD
    const int bs = G / 8;
    const int b0 = blockIdx.y * bs;
    float s = 0.f;
    for (int b = b0; b < b0 + bs; ++b) s += partial[(size_t)b * KD + j];
    atomicAdd(&out[j], s);
}

// ---------------------------------------------------------------- launch ---
extern "C" void kernel_launch(void* const* d_in, const int* in_sizes, int n_in,
                              void* d_out, int out_size, void* d_ws, size_t ws_size,
                              hipStream_t stream) {
    const float* x = (const float*)d_in[0];
    const float* c = (const float*)d_in[1];
    float* out = (float*)d_out;
    const int N = in_sizes[0] / D;

    const size_t idxBytes = ((size_t)N * sizeof(int) + 255) & ~(size_t)255;
    int*   idx     = (int*)d_ws;
    float* partial = (float*)((char*)d_ws + idxBytes);
    const size_t need = idxBytes + (size_t)S_GRID * KD * sizeof(float);
    const int useAtomic = (ws_size < need) ? 1 : 0;

    hipMemsetAsync(d_out, 0, (size_t)out_size * sizeof(float), stream);
    k_assign<<<A_GRID, A_BLK, 0, stream>>>(x, c, idx, out, N);
    k_scatter<<<S_GRID, S_BLK, 0, stream>>>(x, idx, partial, out, N, useAtomic);
    if (!useAtomic) {
        k_reduce<<<dim3(KD / 256, 8), 256, 0, stream>>>(partial, out, S_GRID);
    }
}

// Round 10
// 246.050 us; speedup vs baseline: 1.1147x; 1.1147x over previous
//
#include <hip/hip_runtime.h>

// k-means cluster step: N=400000, D=256, K=50 (fp32 in/out).
// FUSED single-pass design (round 9 ablation: counted-vmcnt pipelines did
// not move the ~3.2TB/s-per-pass ceiling -> stop optimizing 2 passes, halve
// the bytes). One kernel reads x ONCE:
//   per 32-pt chunk, software-pipelined across iterations:
//     waves 0-7 : phase-A(i)  scores = X*C^T (mfma 16x16x32 f16, full K,
//                 pt2 x ncl4), per-tile argmin -> sredm/sredb
//     all waves : phase-B(i-1) sums += onehot(sidx)^T * X from the SAME
//                 staged LDS chunk (1 n-tile/wave x 4 m-tiles, 16 acc VGPRs)
//     wave 15   : combine argmin -> sidx LDS (+ LDS counts)
//   idx never touches HBM. Ring-3 staging (slots i+1/i/i-1 distinct mod 3),
//   2 barriers/chunk, vmcnt(2) keeps the prefetch in flight.
// Staging XOR key (row&7)^(((row>>3)&1)<<2) serves BOTH read patterns at
// the conflict-free floor (row-wise b128 A-frags, column-wise b32 B-frags).

typedef _Float16 f16x8 __attribute__((ext_vector_type(8)));
typedef float    f32x4 __attribute__((ext_vector_type(4)));
typedef int      i32x4 __attribute__((ext_vector_type(4)));

constexpr int K = 50, KP = 64, D = 256, KD = K * D;
constexpr int BLK = 1024, GRID = 256, CH = 32;

#define AS_GLB(p) (const __attribute__((address_space(1))) void*)(p)
#define AS_LDS(p) (__attribute__((address_space(3))) void*)(p)
#define VMCNT_(n) asm volatile("s_waitcnt vmcnt(" #n ")" ::: "memory")
#define LGKM0     asm volatile("s_waitcnt lgkmcnt(0)" ::: "memory")
#define SBAR      { __builtin_amdgcn_sched_barrier(0); __builtin_amdgcn_s_barrier(); __builtin_amdgcn_sched_barrier(0); }

__global__ __launch_bounds__(BLK)
void k_fused(const float* __restrict__ x, const float* __restrict__ cc,
             float* __restrict__ partial, float* __restrict__ out,
             int N, int useAtomic) {
    __shared__ _Float16 sC[KP * D];        // 32 KB, chunk-XOR swizzle ^(r&7)
    __shared__ float    sx[3][CH * D];     // 96 KB ring-3 staging
    __shared__ float    sc2[KP];
    __shared__ float    sredm[4][CH];
    __shared__ int      sredb[4][CH];
    __shared__ int      sidx[2][CH];       // ping-pong per-chunk assignments
    __shared__ int      scnt[K];

    const int tid = threadIdx.x;
    for (int i = tid; i < KP * D; i += BLK) sC[i] = (_Float16)0.f;
    if (tid < K) scnt[tid] = 0;
    __syncthreads();
    for (int i = tid; i < KD; i += BLK) {
        int r = i >> 8, col = i & 255, ch = col >> 3, wd = col & 7;
        sC[r * D + (((ch ^ (r & 7)) << 3) | wd)] = (_Float16)cc[i];
    }
    if (tid < KP) {
        float s = 0.f;
        if (tid < K) for (int q = 0; q < D; ++q) { float v = cc[tid * D + q]; s += v * v; }
        sc2[tid] = s;
    }
    __syncthreads();

    const int lane = tid & 63, ci = lane & 15, g = lane >> 4, w = tid >> 6;
    // phase-A role (waves 0-7): m-tile pt, cluster n-tile ncl, full K
    const int pt   = w & 1, ncl = w >> 1;
    const int arow = pt * 16 + ci;
    const int akey = (ci & 7) ^ (((ci >> 3) & 1) << 2);   // = key(arow)
    const int cr   = ncl * 16 + ci;
    const int ckey = ci & 7;
    // phase-B role (all 16 waves): output n-tile = w (16 cols)
    const int bcol = w * 16 + ci;
    const int c4   = (bcol >> 2) ^ ((g & 1) << 2);        // ^ key-part of row
    const int e    = bcol & 3;

    const int nCh = N / CH;
    const int cpb = nCh / gridDim.x, rem = nCh % gridDim.x;
    const int bid = blockIdx.x;
    const int lo  = bid * cpb + (bid < rem ? bid : rem);
    const int cnt = cpb + (bid < rem ? 1 : 0);

    const float INF = 3.4e38f;
    const float c2v = (cr < K) ? sc2[cr] : INF;

    // stage rows 2w,2w+1 of chunk t_ into slot s_; src pre-swizzled in 16B
    // chunks by key(row) = (row&7) ^ (((row>>3)&1)<<2)
#define STAGE(s_, t_) { \
    const float* base_ = x + (size_t)(t_) * (CH * D); \
    _Pragma("unroll") \
    for (int r2 = 0; r2 < 2; ++r2) { \
        const int row_ = 2 * w + r2; \
        const int key_ = (row_ & 7) ^ (((row_ >> 3) & 1) << 2); \
        const float* src_ = base_ + row_ * D + ((lane ^ key_) << 2); \
        __builtin_amdgcn_global_load_lds(AS_GLB(src_), AS_LDS(&sx[s_][row_ * D]), 16, 0, 0); } }

    f32x4 bacc0 = {0,0,0,0}, bacc1 = {0,0,0,0}, bacc2 = {0,0,0,0}, bacc3 = {0,0,0,0};

    if (cnt > 0) STAGE(0, lo)

    for (int i = 0; i <= cnt; ++i) {
        // prefetch-1: slots (i+1)%3 write, i%3 phase-A read, (i-1)%3 phase-B
        // read -- all distinct mod 3. vmcnt(2) = stage(i) landed, stage(i+1)
        // still in flight (2 global_load_lds per wave per chunk).
        if (i + 1 < cnt) { STAGE((i + 1) % 3, lo + i + 1) VMCNT_(2); }
        else             { VMCNT_(0); }
        SBAR;

        if (w < 8 && i < cnt) {          // ---- phase-A: score chunk i ----
            const float* xb = &sx[i % 3][0];
            f32x4 acc = {0,0,0,0};
#define A_KS(ks) { \
            f32x4 u0 = *(const f32x4*)(xb + arow * D + ((((ks)*8 + 2*g + 0) ^ akey) << 2)); \
            f32x4 u1 = *(const f32x4*)(xb + arow * D + ((((ks)*8 + 2*g + 1) ^ akey) << 2)); \
            f16x8 a = {(_Float16)u0[0], (_Float16)u0[1], (_Float16)u0[2], (_Float16)u0[3], \
                       (_Float16)u1[0], (_Float16)u1[1], (_Float16)u1[2], (_Float16)u1[3]}; \
            f16x8 b = *(const f16x8*)(&sC[cr * D + ((((ks)*4 + g) ^ ckey) << 3)]); \
            acc = __builtin_amdgcn_mfma_f32_16x16x32_f16(a, b, acc, 0, 0, 0); }
            A_KS(0) A_KS(1) A_KS(2) A_KS(3) A_KS(4) A_KS(5) A_KS(6) A_KS(7)
#undef A_KS
            // per-tile argmin, first-min (smallest cluster) tie-break
#define AMIN(r) { \
            float m_ = c2v - 2.f * acc[r]; int b_ = cr; \
            float pm_; int pb_; \
            pm_ = __shfl_xor(m_, 1, 64); pb_ = __shfl_xor(b_, 1, 64); \
            if (pm_ < m_ || (pm_ == m_ && pb_ < b_)) { m_ = pm_; b_ = pb_; } \
            pm_ = __shfl_xor(m_, 2, 64); pb_ = __shfl_xor(b_, 2, 64); \
            if (pm_ < m_ || (pm_ == m_ && pb_ < b_)) { m_ = pm_; b_ = pb_; } \
            pm_ = __shfl_xor(m_, 4, 64); pb_ = __shfl_xor(b_, 4, 64); \
            if (pm_ < m_ || (pm_ == m_ && pb_ < b_)) { m_ = pm_; b_ = pb_; } \
            pm_ = __shfl_xor(m_, 8, 64); pb_ = __shfl_xor(b_, 8, 64); \
            if (pm_ < m_ || (pm_ == m_ && pb_ < b_)) { m_ = pm_; b_ = pb_; } \
            if (ci == 0) { sredm[ncl][pt * 16 + 4 * g + (r)] = m_; \
                           sredb[ncl][pt * 16 + 4 * g + (r)] = b_; } }
            AMIN(0) AMIN(1) AMIN(2) AMIN(3)
#undef AMIN
        }

        if (i >= 1) {                    // ---- phase-B: scatter chunk i-1 ----
            const float* xb = &sx[(i - 1) % 3][0];
            const int jb = (i - 1) & 1;
            i32x4 idA = *(const i32x4*)(&sidx[jb][8 * g]);      // broadcast
            i32x4 idB = *(const i32x4*)(&sidx[jb][8 * g + 4]);
            // b-frag element j = x[8g+j][bcol]; phys chunk = (bcol>>2)^key(row)
#define RDJ(j) xb[(8 * g + (j)) * D + ((c4 ^ (j)) << 2) + e]
            float f0 = RDJ(0), f1 = RDJ(1), f2 = RDJ(2), f3 = RDJ(3);
            float f4 = RDJ(4), f5 = RDJ(5), f6 = RDJ(6), f7 = RDJ(7);
#undef RDJ
            f16x8 b = {(_Float16)f0, (_Float16)f1, (_Float16)f2, (_Float16)f3,
                       (_Float16)f4, (_Float16)f5, (_Float16)f6, (_Float16)f7};
#define BMT(M, ACC) { \
            const int cl_ = (M) * 16 + ci; \
            f16x8 a = {(_Float16)(idA[0] == cl_ ? 1.f : 0.f), (_Float16)(idA[1] == cl_ ? 1.f : 0.f), \
                       (_Float16)(idA[2] == cl_ ? 1.f : 0.f), (_Float16)(idA[3] == cl_ ? 1.f : 0.f), \
                       (_Float16)(idB[0] == cl_ ? 1.f : 0.f), (_Float16)(idB[1] == cl_ ? 1.f : 0.f), \
                       (_Float16)(idB[2] == cl_ ? 1.f : 0.f), (_Float16)(idB[3] == cl_ ? 1.f : 0.f)}; \
            ACC = __builtin_amdgcn_mfma_f32_16x16x32_f16(a, b, ACC, 0, 0, 0); }
            BMT(0, bacc0) BMT(1, bacc1) BMT(2, bacc2) BMT(3, bacc3)
#undef BMT
        }

        LGKM0; SBAR;

        if (i < cnt && w == 15 && lane < 32) {   // ---- combine -> sidx ----
            float bm = sredm[0][lane]; int bb = sredb[0][lane];
            for (int n2 = 1; n2 < 4; ++n2) {
                float mm = sredm[n2][lane]; int bi = sredb[n2][lane];
                if (mm < bm || (mm == bm && bi < bb)) { bm = mm; bb = bi; }
            }
            sidx[i & 1][lane] = bb;
            atomicAdd(&scnt[bb], 1);
        }
        LGKM0;   // wave-15 ds_writes drained before next iter's barrier
    }

    // ---- writeback: D row = M*16+4g+r (cluster), col = bcol ----
    if (useAtomic) {
#define WB(M, ACC) { \
        { int cl_ = (M)*16 + 4*g + 0; if (cl_ < K) atomicAdd(&out[cl_ * D + bcol], ACC[0]); } \
        { int cl_ = (M)*16 + 4*g + 1; if (cl_ < K) atomicAdd(&out[cl_ * D + bcol], ACC[1]); } \
        { int cl_ = (M)*16 + 4*g + 2; if (cl_ < K) atomicAdd(&out[cl_ * D + bcol], ACC[2]); } \
        { int cl_ = (M)*16 + 4*g + 3; if (cl_ < K) atomicAdd(&out[cl_ * D + bcol], ACC[3]); } }
        WB(0, bacc0) WB(1, bacc1) WB(2, bacc2) WB(3, bacc3)
#undef WB
    } else {
        float* pb = partial + (size_t)bid * KD;
#define WB(M, ACC) { \
        { int cl_ = (M)*16 + 4*g + 0; if (cl_ < K) pb[cl_ * D + bcol] = ACC[0]; } \
        { int cl_ = (M)*16 + 4*g + 1; if (cl_ < K) pb[cl_ * D + bcol] = ACC[1]; } \
        { int cl_ = (M)*16 + 4*g + 2; if (cl_ < K) pb[cl_ * D + bcol] = ACC[2]; } \
        { int cl_ = (M)*16 + 4*g + 3; if (cl_ < K) pb[cl_ * D + bcol] = ACC[3]; } }
        WB(0, bacc0) WB(1, bacc1) WB(2, bacc2) WB(3, bacc3)
#undef WB
    }
    __syncthreads();
    for (int k = tid; k < K; k += BLK) atomicAdd(&out[KD + k], (float)scnt[k]);
}

// deterministic partial reduction: one thread owns out[j], sums 256 partials
__global__ __launch_bounds__(256)
void k_reduce(const float* __restrict__ partial, float* __restrict__ out, int G) {
    const int j = blockIdx.x * 256 + threadIdx.x;
    if (j >= KD) return;
    float s = 0.f;
    for (int b = 0; b < G; ++b) s += partial[(size_t)b * KD + j];
    out[j] = s;
}

extern "C" void kernel_launch(void* const* d_in, const int* in_sizes, int n_in,
                              void* d_out, int out_size, void* d_ws, size_t ws_size,
                              hipStream_t stream) {
    const float* x = (const float*)d_in[0];
    const float* c = (const float*)d_in[1];
    float* out = (float*)d_out;
    const int N = in_sizes[0] / D;

    float* partial = (float*)d_ws;
    const size_t need = (size_t)GRID * KD * sizeof(float);
    const int useAtomic = (ws_size < need) ? 1 : 0;

    hipMemsetAsync(d_out, 0, (size_t)out_size * sizeof(float), stream);
    k_fused<<<GRID, BLK, 0, stream>>>(x, c, partial, out, N, useAtomic);
    if (!useAtomic) {
        k_reduce<<<(KD + 255) / 256, 256, 0, stream>>>(partial, out, GRID);
    }
}

// Round 11
// 181.237 us; speedup vs baseline: 1.5134x; 1.3576x over previous
//
#include <hip/hip_runtime.h>

// k-means cluster step: N=400000, D=256, K=50 (fp32 in/out).
// Fused single-pass, LDS-pipe-minimized (round 10 analysis: LDS instrs were
// the serial bottleneck at ~5.5K cy/chunk vs 3.1K cy HBM floor):
//  - x staged as F16 by reg-staging (load->cvt->ds_write_b64, swizzled on
//    the write side) -> phase-A a-frag = 1 ds_read_b128 per k-step.
//  - argmin via score-dump to sS[32][68] + dedicated waves 14/15 (4 b128
//    reads + 2 shfls) instead of 256 ds_swizzle butterflies.
//  - phase-B onehot-GEMM unchanged (validated rounds 7-10), f16 scalar reads.
//  - ring-3 f16 slots, 2 raw barriers/chunk, loads issued 1 full iter early.

typedef _Float16 f16x8 __attribute__((ext_vector_type(8)));
typedef _Float16 f16x4 __attribute__((ext_vector_type(4)));
typedef float    f32x4 __attribute__((ext_vector_type(4)));
typedef int      i32x4 __attribute__((ext_vector_type(4)));
typedef unsigned int u32x4 __attribute__((ext_vector_type(4)));

constexpr int K = 50, KP = 64, D = 256, KD = K * D;
constexpr int BLK = 1024, GRID = 256, CH = 32;
constexpr int SST = 68;   // sS row stride: 272B -> 16B-aligned b128, 2-way banks

#define VMCNT0 asm volatile("s_waitcnt vmcnt(0)" ::: "memory")
#define LGKM0  asm volatile("s_waitcnt lgkmcnt(0)" ::: "memory")
#define SBAR   { __builtin_amdgcn_sched_barrier(0); __builtin_amdgcn_s_barrier(); __builtin_amdgcn_sched_barrier(0); }

__global__ __launch_bounds__(BLK)
void k_fused(const float* __restrict__ x, const float* __restrict__ cc,
             float* __restrict__ partial, float* __restrict__ out,
             int N, int useAtomic) {
    __shared__ _Float16       sC[KP * D];       // 32 KB, chunk-XOR swizzle ^(r&7)
    __shared__ unsigned short sxh[3][CH * D];   // 48 KB f16 ring-3
    __shared__ float          sS[32 * SST];     // 8.5 KB score dump
    __shared__ float          sc2[KP];
    __shared__ int            sidx[2][CH];
    __shared__ int            scnt[K];

    const int tid = threadIdx.x;
    for (int i = tid; i < KP * D; i += BLK) sC[i] = (_Float16)0.f;
    if (tid < K) scnt[tid] = 0;
    __syncthreads();
    for (int i = tid; i < KD; i += BLK) {
        int r = i >> 8, col = i & 255, ch = col >> 3, wd = col & 7;
        sC[r * D + (((ch ^ (r & 7)) << 3) | wd)] = (_Float16)cc[i];
    }
    if (tid < KP) {
        float s = 0.f;
        if (tid < K) for (int q = 0; q < D; ++q) { float v = cc[tid * D + q]; s += v * v; }
        sc2[tid] = s;
    }
    __syncthreads();

    const int lane = tid & 63, ci = lane & 15, g = lane >> 4, w = tid >> 6;
    // phase-A role (waves 0-7): pt = w&1 (point half), ncl = w>>1 (cluster tile)
    const int pt = w & 1, ncl = w >> 1;
    const int arow = pt * 16 + ci;
    const int akey = (ci & 7) ^ (((ci >> 3) & 1) << 2);  // key(arow)==key(ci)
    const int cl   = ncl * 16 + ci;
    const int ckey = ci & 7;
    // phase-B role (all 16 waves): output n-tile w
    const int bcol = w * 16 + ci, bc3 = bcol >> 3, bce = bcol & 7;

    const int nCh = N / CH;
    const int cpb = nCh / gridDim.x, rem = nCh % gridDim.x;
    const int bid = blockIdx.x;
    const int lo  = bid * cpb + (bid < rem ? bid : rem);
    const int cnt = cpb + (bid < rem ? 1 : 0);

    const float INF = 3.4e38f;
    const float c2v = (cl < K) ? sc2[cl] : INF;

    // reg staging: wave w owns rows 2w, 2w+1; lane covers f32 elems 4l..4l+3
    f32x4 rA = {0,0,0,0}, rB = {0,0,0,0};
#define ISSUE(t_) { const float* b_ = x + (size_t)(t_) * (CH * D); \
    rA = *(const f32x4*)(b_ + (2 * w) * D + 4 * lane); \
    rB = *(const f32x4*)(b_ + (2 * w + 1) * D + 4 * lane); }
    // f16 write, swizzled: logical 16B chunk (l>>1) -> phys (l>>1)^key(row)
#define WSLOT(s_) { \
    const int r0_ = 2 * w, r1_ = 2 * w + 1; \
    const int lc_ = lane >> 1, hf_ = (lane & 1) * 4; \
    const int k0_ = (r0_ & 7) ^ (((r0_ >> 3) & 1) << 2); \
    const int k1_ = (r1_ & 7) ^ (((r1_ >> 3) & 1) << 2); \
    f16x4 h0 = {(_Float16)rA[0], (_Float16)rA[1], (_Float16)rA[2], (_Float16)rA[3]}; \
    f16x4 h1 = {(_Float16)rB[0], (_Float16)rB[1], (_Float16)rB[2], (_Float16)rB[3]}; \
    *(f16x4*)(&sxh[s_][r0_ * D + ((lc_ ^ k0_) << 3) + hf_]) = h0; \
    *(f16x4*)(&sxh[s_][r1_ * D + ((lc_ ^ k1_) << 3) + hf_]) = h1; }

    f32x4 bacc0 = {0,0,0,0}, bacc1 = {0,0,0,0}, bacc2 = {0,0,0,0}, bacc3 = {0,0,0,0};

    // prologue: slot0 <- chunk lo; issue chunk lo+1
    ISSUE(lo)
    VMCNT0;
    WSLOT(0)
    if (cnt > 1) ISSUE(lo + 1)
    LGKM0; SBAR;

    for (int i = 0; i <= cnt; ++i) {
        // top: write chunk i+1 (loads issued a full iteration ago), then
        // issue chunk i+2. Slot (i+1)%3 had its last reader (phase-B(i-2))
        // finish before the final barrier of iter i-1.
        if (i + 1 < cnt) { VMCNT0; WSLOT((i + 1) % 3) }
        if (i + 2 < cnt) ISSUE(lo + i + 2)

        if (w < 8 && i < cnt) {          // ---- phase A: score chunk i ----
            const unsigned short* xb = &sxh[i % 3][0];
            f32x4 acc = {0,0,0,0};
#define A_KS(ks) { \
            f16x8 a = *(const f16x8*)(&xb[arow * D + ((((ks) * 4 + g) ^ akey) << 3)]); \
            f16x8 b = *(const f16x8*)(&sC[cl * D + ((((ks) * 4 + g) ^ ckey) << 3)]); \
            acc = __builtin_amdgcn_mfma_f32_16x16x32_f16(a, b, acc, 0, 0, 0); }
            A_KS(0) A_KS(1) A_KS(2) A_KS(3) A_KS(4) A_KS(5) A_KS(6) A_KS(7)
#undef A_KS
            // dump scores: row = pt*16+4g+r (point), col = cl (cluster)
            sS[(pt * 16 + 4 * g + 0) * SST + cl] = c2v - 2.f * acc[0];
            sS[(pt * 16 + 4 * g + 1) * SST + cl] = c2v - 2.f * acc[1];
            sS[(pt * 16 + 4 * g + 2) * SST + cl] = c2v - 2.f * acc[2];
            sS[(pt * 16 + 4 * g + 3) * SST + cl] = c2v - 2.f * acc[3];
        }

        if (i >= 1) {                    // ---- phase B: scatter chunk i-1 ----
            const unsigned short* xbh = &sxh[(i + 2) % 3][0];  // == (i-1)%3
            const int jb = (i - 1) & 1;
            i32x4 idA = *(const i32x4*)(&sidx[jb][8 * g]);     // broadcast
            i32x4 idB = *(const i32x4*)(&sidx[jb][8 * g + 4]);
            unsigned short v0, v1, v2, v3, v4, v5, v6, v7;
#define RDH(j) { const int p_ = 8 * g + (j); const int key_ = (j) ^ ((g & 1) << 2); \
            v##j = xbh[p_ * D + ((bc3 ^ key_) << 3) + bce]; }
            RDH(0) RDH(1) RDH(2) RDH(3) RDH(4) RDH(5) RDH(6) RDH(7)
#undef RDH
            unsigned int w0 = (unsigned int)v0 | ((unsigned int)v1 << 16);
            unsigned int w1 = (unsigned int)v2 | ((unsigned int)v3 << 16);
            unsigned int w2 = (unsigned int)v4 | ((unsigned int)v5 << 16);
            unsigned int w3 = (unsigned int)v6 | ((unsigned int)v7 << 16);
            u32x4 W = {w0, w1, w2, w3};
            f16x8 bfr = __builtin_bit_cast(f16x8, W);
#define BMT(M, ACC) { \
            const int cl_ = (M) * 16 + ci; \
            f16x8 a = {(_Float16)(idA[0] == cl_ ? 1.f : 0.f), (_Float16)(idA[1] == cl_ ? 1.f : 0.f), \
                       (_Float16)(idA[2] == cl_ ? 1.f : 0.f), (_Float16)(idA[3] == cl_ ? 1.f : 0.f), \
                       (_Float16)(idB[0] == cl_ ? 1.f : 0.f), (_Float16)(idB[1] == cl_ ? 1.f : 0.f), \
                       (_Float16)(idB[2] == cl_ ? 1.f : 0.f), (_Float16)(idB[3] == cl_ ? 1.f : 0.f)}; \
            ACC = __builtin_amdgcn_mfma_f32_16x16x32_f16(a, bfr, ACC, 0, 0, 0); }
            BMT(0, bacc0) BMT(1, bacc1) BMT(2, bacc2) BMT(3, bacc3)
#undef BMT
        }

        LGKM0; SBAR;   // scores(i) + slot(i+1) writes visible

        if (w >= 14 && i < cnt) {        // ---- argmin chunk i (waves 14/15) ----
            const int p_ = (w - 14) * 16 + (lane & 15);   // point 0..31
            const int kq = lane >> 4;                      // cluster quarter
            const float* sp = &sS[p_ * SST + kq * 16];
            f32x4 s0 = *(const f32x4*)(sp);
            f32x4 s1 = *(const f32x4*)(sp + 4);
            f32x4 s2 = *(const f32x4*)(sp + 8);
            f32x4 s3 = *(const f32x4*)(sp + 12);
            float bm = s0[0]; int bb = kq * 16;
#define CMP(V, E, OFF) { float s_ = V[E]; int c_ = kq * 16 + (OFF); \
            if (s_ < bm) { bm = s_; bb = c_; } }
            CMP(s0,1,1) CMP(s0,2,2) CMP(s0,3,3)
            CMP(s1,0,4) CMP(s1,1,5) CMP(s1,2,6) CMP(s1,3,7)
            CMP(s2,0,8) CMP(s2,1,9) CMP(s2,2,10) CMP(s2,3,11)
            CMP(s3,0,12) CMP(s3,1,13) CMP(s3,2,14) CMP(s3,3,15)
#undef CMP
            { float pm = __shfl_xor(bm, 16, 64); int pb = __shfl_xor(bb, 16, 64);
              if (pm < bm || (pm == bm && pb < bb)) { bm = pm; bb = pb; } }
            { float pm = __shfl_xor(bm, 32, 64); int pb = __shfl_xor(bb, 32, 64);
              if (pm < bm || (pm == bm && pb < bb)) { bm = pm; bb = pb; } }
            if (kq == 0) { sidx[i & 1][p_] = bb; atomicAdd(&scnt[bb], 1); }
        }
        LGKM0; SBAR;   // sidx(i) visible for phase-B in iter i+1
    }

    // ---- writeback: D row = M*16+4g+r (cluster), col = bcol ----
    if (useAtomic) {
#define WBK(M, ACC) { \
        { int cl_ = (M)*16 + 4*g + 0; if (cl_ < K) atomicAdd(&out[cl_ * D + bcol], ACC[0]); } \
        { int cl_ = (M)*16 + 4*g + 1; if (cl_ < K) atomicAdd(&out[cl_ * D + bcol], ACC[1]); } \
        { int cl_ = (M)*16 + 4*g + 2; if (cl_ < K) atomicAdd(&out[cl_ * D + bcol], ACC[2]); } \
        { int cl_ = (M)*16 + 4*g + 3; if (cl_ < K) atomicAdd(&out[cl_ * D + bcol], ACC[3]); } }
        WBK(0, bacc0) WBK(1, bacc1) WBK(2, bacc2) WBK(3, bacc3)
#undef WBK
    } else {
        float* pb = partial + (size_t)bid * KD;
#define WBK(M, ACC) { \
        { int cl_ = (M)*16 + 4*g + 0; if (cl_ < K) pb[cl_ * D + bcol] = ACC[0]; } \
        { int cl_ = (M)*16 + 4*g + 1; if (cl_ < K) pb[cl_ * D + bcol] = ACC[1]; } \
        { int cl_ = (M)*16 + 4*g + 2; if (cl_ < K) pb[cl_ * D + bcol] = ACC[2]; } \
        { int cl_ = (M)*16 + 4*g + 3; if (cl_ < K) pb[cl_ * D + bcol] = ACC[3]; } }
        WBK(0, bacc0) WBK(1, bacc1) WBK(2, bacc2) WBK(3, bacc3)
#undef WBK
    }
    __syncthreads();
    for (int k = tid; k < K; k += BLK) atomicAdd(&out[KD + k], (float)scnt[k]);
}

// deterministic partial reduction: one thread owns out[j]
__global__ __launch_bounds__(256)
void k_reduce(const float* __restrict__ partial, float* __restrict__ out, int G) {
    const int j = blockIdx.x * 256 + threadIdx.x;
    if (j >= KD) return;
    float s = 0.f;
    for (int b = 0; b < G; ++b) s += partial[(size_t)b * KD + j];
    out[j] = s;
}

extern "C" void kernel_launch(void* const* d_in, const int* in_sizes, int n_in,
                              void* d_out, int out_size, void* d_ws, size_t ws_size,
                              hipStream_t stream) {
    const float* x = (const float*)d_in[0];
    const float* c = (const float*)d_in[1];
    float* out = (float*)d_out;
    const int N = in_sizes[0] / D;

    float* partial = (float*)d_ws;
    const size_t need = (size_t)GRID * KD * sizeof(float);
    const int useAtomic = (ws_size < need) ? 1 : 0;

    hipMemsetAsync(d_out, 0, (size_t)out_size * sizeof(float), stream);
    k_fused<<<GRID, BLK, 0, stream>>>(x, c, partial, out, N, useAtomic);
    if (!useAtomic) {
        k_reduce<<<(KD + 255) / 256, 256, 0, stream>>>(partial, out, GRID);
    }
}

// Round 12
// 176.842 us; speedup vs baseline: 1.5510x; 1.0249x over previous
//
#include <hip/hip_runtime.h>

// k-means cluster step: N=400000, D=256, K=50 (fp32 in/out).
// Fused single-pass (round 11 + phase-A on 32x32 MFMA):
//  - phase A: scores = X*C^T via mfma_f32_32x32x16_f16. 2 waves (14,15) cover
//    the full 32-pt x 64-cl chunk -> zero x/C LDS read redundancy
//    (64 b128 reads/chunk vs 128 with the 16x16 pt2 x ncl4 grid).
//  - argmin: waves 8,9 from the sS score dump (round-11 code).
//  - phase B: onehot(sidx)^T * X on all 16 waves (round-11 code verbatim).
//  - staging: all 16 waves, 2 rows each, reg->f16->ds_write, ring-3.

typedef _Float16 f16x8 __attribute__((ext_vector_type(8)));
typedef _Float16 f16x4 __attribute__((ext_vector_type(4)));
typedef float    f32x4 __attribute__((ext_vector_type(4)));
typedef float    f32x16 __attribute__((ext_vector_type(16)));
typedef int      i32x4 __attribute__((ext_vector_type(4)));
typedef unsigned int u32x4 __attribute__((ext_vector_type(4)));

constexpr int K = 50, KP = 64, D = 256, KD = K * D;
constexpr int BLK = 1024, GRID = 256, CH = 32;
constexpr int SST = 68;   // sS row stride (f32): 272B, 16B-aligned, ~2-way banks

#define VMCNT0 asm volatile("s_waitcnt vmcnt(0)" ::: "memory")
#define LGKM0  asm volatile("s_waitcnt lgkmcnt(0)" ::: "memory")
#define SBAR   { __builtin_amdgcn_sched_barrier(0); __builtin_amdgcn_s_barrier(); __builtin_amdgcn_sched_barrier(0); }

__global__ __launch_bounds__(BLK)
void k_fused(const float* __restrict__ x, const float* __restrict__ cc,
             float* __restrict__ partial, float* __restrict__ out,
             int N, int useAtomic) {
    __shared__ _Float16       sC[KP * D];       // 32 KB, 8-f16-chunk XOR ^(r&7)
    __shared__ unsigned short sxh[3][CH * D];   // 48 KB f16 ring-3
    __shared__ float          sS[32 * SST];     // 8.7 KB score dump
    __shared__ float          sc2[KP];
    __shared__ int            sidx[2][CH];
    __shared__ int            scnt[K];

    const int tid = threadIdx.x;
    for (int i = tid; i < KP * D; i += BLK) sC[i] = (_Float16)0.f;
    if (tid < K) scnt[tid] = 0;
    __syncthreads();
    for (int i = tid; i < KD; i += BLK) {
        int r = i >> 8, col = i & 255, ch = col >> 3, wd = col & 7;
        sC[r * D + (((ch ^ (r & 7)) << 3) | wd)] = (_Float16)cc[i];
    }
    if (tid < KP) {
        float s = 0.f;
        if (tid < K) for (int q = 0; q < D; ++q) { float v = cc[tid * D + q]; s += v * v; }
        sc2[tid] = s;
    }
    __syncthreads();

    const int lane = tid & 63, ci = lane & 15, g = lane >> 4, w = tid >> 6;
    // phase-A role (waves 14,15): one 32x32 tile each (cls 0-31 / 32-63)
    const int wA   = (w >= 14) ? (w - 14) : 0;
    const int ra   = lane & 31;               // point row
    const int dl   = lane >> 5;               // k-subgroup
    const int rakey = (ra & 7) ^ (((ra >> 3) & 1) << 2);
    const int cl32 = wA * 32 + (lane & 31);   // cluster col
    const int clkey = (lane & 31) & 7;
    // phase-B role (all 16 waves): output n-tile w
    const int bcol = w * 16 + ci, bc3 = bcol >> 3, bce = bcol & 7;

    const int nCh = N / CH;
    const int cpb = nCh / gridDim.x, rem = nCh % gridDim.x;
    const int bid = blockIdx.x;
    const int lo  = bid * cpb + (bid < rem ? bid : rem);
    const int cnt = cpb + (bid < rem ? 1 : 0);

    const float INF = 3.4e38f;
    const float c2A = (cl32 < K) ? sc2[cl32] : INF;

    // reg staging: wave w owns rows 2w, 2w+1; lane covers f32 elems 4l..4l+3
    f32x4 rA = {0,0,0,0}, rB = {0,0,0,0};
#define ISSUE(t_) { const float* b_ = x + (size_t)(t_) * (CH * D); \
    rA = *(const f32x4*)(b_ + (2 * w) * D + 4 * lane); \
    rB = *(const f32x4*)(b_ + (2 * w + 1) * D + 4 * lane); }
#define WSLOT(s_) { \
    const int r0_ = 2 * w, r1_ = 2 * w + 1; \
    const int lc_ = lane >> 1, hf_ = (lane & 1) * 4; \
    const int k0_ = (r0_ & 7) ^ (((r0_ >> 3) & 1) << 2); \
    const int k1_ = (r1_ & 7) ^ (((r1_ >> 3) & 1) << 2); \
    f16x4 h0 = {(_Float16)rA[0], (_Float16)rA[1], (_Float16)rA[2], (_Float16)rA[3]}; \
    f16x4 h1 = {(_Float16)rB[0], (_Float16)rB[1], (_Float16)rB[2], (_Float16)rB[3]}; \
    *(f16x4*)(&sxh[s_][r0_ * D + ((lc_ ^ k0_) << 3) + hf_]) = h0; \
    *(f16x4*)(&sxh[s_][r1_ * D + ((lc_ ^ k1_) << 3) + hf_]) = h1; }

    f32x4 bacc0 = {0,0,0,0}, bacc1 = {0,0,0,0}, bacc2 = {0,0,0,0}, bacc3 = {0,0,0,0};

    // prologue
    if (cnt > 0) { ISSUE(lo) VMCNT0; WSLOT(0) if (cnt > 1) ISSUE(lo + 1) }
    LGKM0; SBAR;

    for (int i = 0; i <= cnt; ++i) {
        // seg1: write chunk i+1 (loads issued a full iter ago); issue i+2.
        // Slot (i+1)%3's last reader was phase-B(i-2) in iter i-1 (barriered).
        if (i + 1 < cnt) { VMCNT0; WSLOT((i + 1) % 3) }
        if (i + 2 < cnt) ISSUE(lo + i + 2)

        if (w >= 14 && i < cnt) {        // ---- phase A: 32x32 MFMA, waves 14/15
            const unsigned short* xb = &sxh[i % 3][0];
            f32x16 acc = {0,0,0,0,0,0,0,0,0,0,0,0,0,0,0,0};
#define A_KS(ks) { \
            const int c_ = (ks) * 2 + dl; \
            f16x8 a = *(const f16x8*)(&xb[ra * D + ((c_ ^ rakey) << 3)]); \
            f16x8 b = *(const f16x8*)(&sC[cl32 * D + ((c_ ^ clkey) << 3)]); \
            acc = __builtin_amdgcn_mfma_f32_32x32x16_f16(a, b, acc, 0, 0, 0); }
            A_KS(0) A_KS(1) A_KS(2) A_KS(3) A_KS(4) A_KS(5) A_KS(6) A_KS(7)
            A_KS(8) A_KS(9) A_KS(10) A_KS(11) A_KS(12) A_KS(13) A_KS(14) A_KS(15)
#undef A_KS
            // dump: row(point) = (r&3)+8*(r>>2)+4*dl, col = cl32
#define DUMP(r) { const int row_ = ((r) & 3) + 8 * ((r) >> 2) + 4 * dl; \
            sS[row_ * SST + cl32] = c2A - 2.f * acc[r]; }
            DUMP(0) DUMP(1) DUMP(2) DUMP(3) DUMP(4) DUMP(5) DUMP(6) DUMP(7)
            DUMP(8) DUMP(9) DUMP(10) DUMP(11) DUMP(12) DUMP(13) DUMP(14) DUMP(15)
#undef DUMP
        }

        if (i >= 1) {                    // ---- phase B: scatter chunk i-1, all waves
            const unsigned short* xbh = &sxh[(i + 2) % 3][0];  // == (i-1)%3
            const int jb = (i - 1) & 1;
            i32x4 idA = *(const i32x4*)(&sidx[jb][8 * g]);     // broadcast
            i32x4 idB = *(const i32x4*)(&sidx[jb][8 * g + 4]);
            unsigned short v0, v1, v2, v3, v4, v5, v6, v7;
#define RDH(j) { const int p_ = 8 * g + (j); const int key_ = (j) ^ ((g & 1) << 2); \
            v##j = xbh[p_ * D + ((bc3 ^ key_) << 3) + bce]; }
            RDH(0) RDH(1) RDH(2) RDH(3) RDH(4) RDH(5) RDH(6) RDH(7)
#undef RDH
            unsigned int w0 = (unsigned int)v0 | ((unsigned int)v1 << 16);
            unsigned int w1 = (unsigned int)v2 | ((unsigned int)v3 << 16);
            unsigned int w2 = (unsigned int)v4 | ((unsigned int)v5 << 16);
            unsigned int w3 = (unsigned int)v6 | ((unsigned int)v7 << 16);
            u32x4 W = {w0, w1, w2, w3};
            f16x8 bfr = __builtin_bit_cast(f16x8, W);
#define BMT(M, ACC) { \
            const int cl_ = (M) * 16 + ci; \
            f16x8 a = {(_Float16)(idA[0] == cl_ ? 1.f : 0.f), (_Float16)(idA[1] == cl_ ? 1.f : 0.f), \
                       (_Float16)(idA[2] == cl_ ? 1.f : 0.f), (_Float16)(idA[3] == cl_ ? 1.f : 0.f), \
                       (_Float16)(idB[0] == cl_ ? 1.f : 0.f), (_Float16)(idB[1] == cl_ ? 1.f : 0.f), \
                       (_Float16)(idB[2] == cl_ ? 1.f : 0.f), (_Float16)(idB[3] == cl_ ? 1.f : 0.f)}; \
            ACC = __builtin_amdgcn_mfma_f32_16x16x32_f16(a, bfr, ACC, 0, 0, 0); }
            BMT(0, bacc0) BMT(1, bacc1) BMT(2, bacc2) BMT(3, bacc3)
#undef BMT
        }

        LGKM0; SBAR;   // scores(i) + WSLOT(i+1) visible

        if (w >= 8 && w < 10 && i < cnt) {   // ---- argmin chunk i, waves 8/9
            const int p_ = (w - 8) * 16 + (lane & 15);
            const int kq = lane >> 4;
            const float* sp = &sS[p_ * SST + kq * 16];
            f32x4 s0 = *(const f32x4*)(sp);
            f32x4 s1 = *(const f32x4*)(sp + 4);
            f32x4 s2 = *(const f32x4*)(sp + 8);
            f32x4 s3 = *(const f32x4*)(sp + 12);
            float bm = s0[0]; int bb = kq * 16;
#define CMP(V, E, OFF) { float s_ = V[E]; int c_ = kq * 16 + (OFF); \
            if (s_ < bm) { bm = s_; bb = c_; } }
            CMP(s0,1,1) CMP(s0,2,2) CMP(s0,3,3)
            CMP(s1,0,4) CMP(s1,1,5) CMP(s1,2,6) CMP(s1,3,7)
            CMP(s2,0,8) CMP(s2,1,9) CMP(s2,2,10) CMP(s2,3,11)
            CMP(s3,0,12) CMP(s3,1,13) CMP(s3,2,14) CMP(s3,3,15)
#undef CMP
            { float pm = __shfl_xor(bm, 16, 64); int pb = __shfl_xor(bb, 16, 64);
              if (pm < bm || (pm == bm && pb < bb)) { bm = pm; bb = pb; } }
            { float pm = __shfl_xor(bm, 32, 64); int pb = __shfl_xor(bb, 32, 64);
              if (pm < bm || (pm == bm && pb < bb)) { bm = pm; bb = pb; } }
            if (kq == 0) { sidx[i & 1][p_] = bb; atomicAdd(&scnt[bb], 1); }
        }
        LGKM0; SBAR;   // sidx(i) visible for phase-B in iter i+1
    }

    // ---- writeback: D row = M*16+4g+r (cluster), col = bcol ----
    if (useAtomic) {
#define WBK(M, ACC) { \
        { int cl_ = (M)*16 + 4*g + 0; if (cl_ < K) atomicAdd(&out[cl_ * D + bcol], ACC[0]); } \
        { int cl_ = (M)*16 + 4*g + 1; if (cl_ < K) atomicAdd(&out[cl_ * D + bcol], ACC[1]); } \
        { int cl_ = (M)*16 + 4*g + 2; if (cl_ < K) atomicAdd(&out[cl_ * D + bcol], ACC[2]); } \
        { int cl_ = (M)*16 + 4*g + 3; if (cl_ < K) atomicAdd(&out[cl_ * D + bcol], ACC[3]); } }
        WBK(0, bacc0) WBK(1, bacc1) WBK(2, bacc2) WBK(3, bacc3)
#undef WBK
    } else {
        float* pb = partial + (size_t)bid * KD;
#define WBK(M, ACC) { \
        { int cl_ = (M)*16 + 4*g + 0; if (cl_ < K) pb[cl_ * D + bcol] = ACC[0]; } \
        { int cl_ = (M)*16 + 4*g + 1; if (cl_ < K) pb[cl_ * D + bcol] = ACC[1]; } \
        { int cl_ = (M)*16 + 4*g + 2; if (cl_ < K) pb[cl_ * D + bcol] = ACC[2]; } \
        { int cl_ = (M)*16 + 4*g + 3; if (cl_ < K) pb[cl_ * D + bcol] = ACC[3]; } }
        WBK(0, bacc0) WBK(1, bacc1) WBK(2, bacc2) WBK(3, bacc3)
#undef WBK
    }
    __syncthreads();
    for (int k = tid; k < K; k += BLK) atomicAdd(&out[KD + k], (float)scnt[k]);
}

// deterministic partial reduction: one thread owns out[j]
__global__ __launch_bounds__(256)
void k_reduce(const float* __restrict__ partial, float* __restrict__ out, int G) {
    const int j = blockIdx.x * 256 + threadIdx.x;
    if (j >= KD) return;
    float s = 0.f;
    for (int b = 0; b < G; ++b) s += partial[(size_t)b * KD + j];
    out[j] = s;
}

extern "C" void kernel_launch(void* const* d_in, const int* in_sizes, int n_in,
                              void* d_out, int out_size, void* d_ws, size_t ws_size,
                              hipStream_t stream) {
    const float* x = (const float*)d_in[0];
    const float* c = (const float*)d_in[1];
    float* out = (float*)d_out;
    const int N = in_sizes[0] / D;

    float* partial = (float*)d_ws;
    const size_t need = (size_t)GRID * KD * sizeof(float);
    const int useAtomic = (ws_size < need) ? 1 : 0;

    hipMemsetAsync(d_out, 0, (size_t)out_size * sizeof(float), stream);
    k_fused<<<GRID, BLK, 0, stream>>>(x, c, partial, out, N, useAtomic);
    if (!useAtomic) {
        k_reduce<<<(KD + 255) / 256, 256, 0, stream>>>(partial, out, GRID);
    }
}

// Round 13
// 143.884 us; speedup vs baseline: 1.9063x; 1.2291x over previous
//
#include <hip/hip_runtime.h>

// k-means cluster step: N=400000, D=256, K=50 (fp32 in/out).
// Round 13 = round 12 + 2 blocks/CU (the lever): round 12 ran 1 block/CU and
// every barrier/stall left the CU idle (~2.5 TB/s effective). LDS cut to
// ~80KB/block (sC 50 rows, f16 score dump) so two 1024-thread blocks
// co-reside; GRID=512. Phase structure unchanged (validated rounds 10-12):
//   staging: reg->f16->ds_write ring-3; phase A: 32x32 MFMA on waves 14/15;
//   argmin: waves 8/9 from score dump; phase B: onehot^T*X on all 16 waves.

typedef _Float16 f16x8 __attribute__((ext_vector_type(8)));
typedef _Float16 f16x4 __attribute__((ext_vector_type(4)));
typedef float    f32x4 __attribute__((ext_vector_type(4)));
typedef float    f32x16 __attribute__((ext_vector_type(16)));
typedef int      i32x4 __attribute__((ext_vector_type(4)));
typedef unsigned int u32x4 __attribute__((ext_vector_type(4)));

constexpr int K = 50, KP = 64, D = 256, KD = K * D;
constexpr int BLK = 1024, GRID = 512, CH = 32;
constexpr int SSTH = 72;   // f16 score stride: 144B rows, 16B-aligned

#define VMCNT0 asm volatile("s_waitcnt vmcnt(0)" ::: "memory")
#define LGKM0  asm volatile("s_waitcnt lgkmcnt(0)" ::: "memory")
#define SBAR   { __builtin_amdgcn_sched_barrier(0); __builtin_amdgcn_s_barrier(); __builtin_amdgcn_sched_barrier(0); }

__global__ __launch_bounds__(BLK)
void k_fused(const float* __restrict__ x, const float* __restrict__ cc,
             float* __restrict__ partial, float* __restrict__ out,
             int N, int useAtomic) {
    __shared__ _Float16       sC[K * D];        // 25.6 KB, 8-f16-chunk XOR ^(r&7)
    __shared__ unsigned short sxh[3][CH * D];   // 48 KB f16 ring-3
    __shared__ _Float16       sSh[32 * SSTH];   // 4.6 KB f16 score dump
    __shared__ float          sc2[KP];
    __shared__ int            sidx[2][CH];
    __shared__ int            scnt[K];

    const int tid = threadIdx.x;
    for (int i = tid; i < K * D; i += BLK) sC[i] = (_Float16)0.f;
    if (tid < K) scnt[tid] = 0;
    __syncthreads();
    for (int i = tid; i < KD; i += BLK) {
        int r = i >> 8, col = i & 255, ch = col >> 3, wd = col & 7;
        sC[r * D + (((ch ^ (r & 7)) << 3) | wd)] = (_Float16)cc[i];
    }
    if (tid < KP) {
        float s = 0.f;
        if (tid < K) for (int q = 0; q < D; ++q) { float v = cc[tid * D + q]; s += v * v; }
        sc2[tid] = s;
    }
    __syncthreads();

    const int lane = tid & 63, ci = lane & 15, g = lane >> 4, w = tid >> 6;
    // phase-A role (waves 14,15): one 32x32 tile each (cls 0-31 / 32-63)
    const int wA   = (w >= 14) ? (w - 14) : 0;
    const int ra   = lane & 31;               // point row
    const int dl   = lane >> 5;               // k-subgroup
    const int rakey = (ra & 7) ^ (((ra >> 3) & 1) << 2);
    const int cl32 = wA * 32 + (lane & 31);   // cluster col (0..63)
    const int clkey = (lane & 31) & 7;
    const _Float16* cbp = &sC[(cl32 < K ? cl32 : K - 1) * D];  // clamped row
    // phase-B role (all 16 waves): output n-tile w
    const int bcol = w * 16 + ci, bc3 = bcol >> 3, bce = bcol & 7;

    const int nCh = N / CH;
    const int cpb = nCh / gridDim.x, rem = nCh % gridDim.x;
    const int bid = blockIdx.x;
    const int lo  = bid * cpb + (bid < rem ? bid : rem);
    const int cnt = cpb + (bid < rem ? 1 : 0);

    const float INF = 3.4e38f;
    const float c2A = (cl32 < K) ? sc2[cl32] : INF;

    // reg staging: wave w owns rows 2w, 2w+1; lane covers f32 elems 4l..4l+3
    f32x4 rA = {0,0,0,0}, rB = {0,0,0,0};
#define ISSUE(t_) { const float* b_ = x + (size_t)(t_) * (CH * D); \
    rA = *(const f32x4*)(b_ + (2 * w) * D + 4 * lane); \
    rB = *(const f32x4*)(b_ + (2 * w + 1) * D + 4 * lane); }
#define WSLOT(s_) { \
    const int r0_ = 2 * w, r1_ = 2 * w + 1; \
    const int lc_ = lane >> 1, hf_ = (lane & 1) * 4; \
    const int k0_ = (r0_ & 7) ^ (((r0_ >> 3) & 1) << 2); \
    const int k1_ = (r1_ & 7) ^ (((r1_ >> 3) & 1) << 2); \
    f16x4 h0 = {(_Float16)rA[0], (_Float16)rA[1], (_Float16)rA[2], (_Float16)rA[3]}; \
    f16x4 h1 = {(_Float16)rB[0], (_Float16)rB[1], (_Float16)rB[2], (_Float16)rB[3]}; \
    *(f16x4*)(&sxh[s_][r0_ * D + ((lc_ ^ k0_) << 3) + hf_]) = h0; \
    *(f16x4*)(&sxh[s_][r1_ * D + ((lc_ ^ k1_) << 3) + hf_]) = h1; }

    f32x4 bacc0 = {0,0,0,0}, bacc1 = {0,0,0,0}, bacc2 = {0,0,0,0}, bacc3 = {0,0,0,0};

    // prologue
    if (cnt > 0) { ISSUE(lo) VMCNT0; WSLOT(0) if (cnt > 1) ISSUE(lo + 1) }
    LGKM0; SBAR;

    for (int i = 0; i <= cnt; ++i) {
        // seg1: write chunk i+1 (loads issued a full iter ago); issue i+2.
        if (i + 1 < cnt) { VMCNT0; WSLOT((i + 1) % 3) }
        if (i + 2 < cnt) ISSUE(lo + i + 2)

        if (w >= 14 && i < cnt) {        // ---- phase A: 32x32 MFMA, waves 14/15
            const unsigned short* xb = &sxh[i % 3][0];
            f32x16 acc = {0,0,0,0,0,0,0,0,0,0,0,0,0,0,0,0};
#define A_KS(ks) { \
            const int c_ = (ks) * 2 + dl; \
            f16x8 a = *(const f16x8*)(&xb[ra * D + ((c_ ^ rakey) << 3)]); \
            f16x8 b = *(const f16x8*)(cbp + ((c_ ^ clkey) << 3)); \
            acc = __builtin_amdgcn_mfma_f32_32x32x16_f16(a, b, acc, 0, 0, 0); }
            A_KS(0) A_KS(1) A_KS(2) A_KS(3) A_KS(4) A_KS(5) A_KS(6) A_KS(7)
            A_KS(8) A_KS(9) A_KS(10) A_KS(11) A_KS(12) A_KS(13) A_KS(14) A_KS(15)
#undef A_KS
            // dump (f16): row(point) = (r&3)+8*(r>>2)+4*dl, col = cl32
#define DUMP(r) { const int row_ = ((r) & 3) + 8 * ((r) >> 2) + 4 * dl; \
            sSh[row_ * SSTH + cl32] = (_Float16)(c2A - 2.f * acc[r]); }
            DUMP(0) DUMP(1) DUMP(2) DUMP(3) DUMP(4) DUMP(5) DUMP(6) DUMP(7)
            DUMP(8) DUMP(9) DUMP(10) DUMP(11) DUMP(12) DUMP(13) DUMP(14) DUMP(15)
#undef DUMP
        }

        if (i >= 1) {                    // ---- phase B: scatter chunk i-1, all waves
            const unsigned short* xbh = &sxh[(i + 2) % 3][0];  // == (i-1)%3
            const int jb = (i - 1) & 1;
            i32x4 idA = *(const i32x4*)(&sidx[jb][8 * g]);     // broadcast
            i32x4 idB = *(const i32x4*)(&sidx[jb][8 * g + 4]);
            unsigned short v0, v1, v2, v3, v4, v5, v6, v7;
#define RDH(j) { const int p_ = 8 * g + (j); const int key_ = (j) ^ ((g & 1) << 2); \
            v##j = xbh[p_ * D + ((bc3 ^ key_) << 3) + bce]; }
            RDH(0) RDH(1) RDH(2) RDH(3) RDH(4) RDH(5) RDH(6) RDH(7)
#undef RDH
            unsigned int w0 = (unsigned int)v0 | ((unsigned int)v1 << 16);
            unsigned int w1 = (unsigned int)v2 | ((unsigned int)v3 << 16);
            unsigned int w2 = (unsigned int)v4 | ((unsigned int)v5 << 16);
            unsigned int w3 = (unsigned int)v6 | ((unsigned int)v7 << 16);
            u32x4 W = {w0, w1, w2, w3};
            f16x8 bfr = __builtin_bit_cast(f16x8, W);
#define BMT(M, ACC) { \
            const int cl_ = (M) * 16 + ci; \
            f16x8 a = {(_Float16)(idA[0] == cl_ ? 1.f : 0.f), (_Float16)(idA[1] == cl_ ? 1.f : 0.f), \
                       (_Float16)(idA[2] == cl_ ? 1.f : 0.f), (_Float16)(idA[3] == cl_ ? 1.f : 0.f), \
                       (_Float16)(idB[0] == cl_ ? 1.f : 0.f), (_Float16)(idB[1] == cl_ ? 1.f : 0.f), \
                       (_Float16)(idB[2] == cl_ ? 1.f : 0.f), (_Float16)(idB[3] == cl_ ? 1.f : 0.f)}; \
            ACC = __builtin_amdgcn_mfma_f32_16x16x32_f16(a, bfr, ACC, 0, 0, 0); }
            BMT(0, bacc0) BMT(1, bacc1) BMT(2, bacc2) BMT(3, bacc3)
#undef BMT
        }

        LGKM0; SBAR;   // scores(i) + WSLOT(i+1) visible

        if (w >= 8 && w < 10 && i < cnt) {   // ---- argmin chunk i, waves 8/9
            const int p_ = (w - 8) * 16 + (lane & 15);
            const int kq = lane >> 4;
            const _Float16* sp = &sSh[p_ * SSTH + kq * 16];
            f16x8 h0 = *(const f16x8*)(sp);
            f16x8 h1 = *(const f16x8*)(sp + 8);
            float bm = (float)h0[0]; int bb = kq * 16;
#define CMP(V, E, OFF) { float s_ = (float)V[E]; int c_ = kq * 16 + (OFF); \
            if (s_ < bm) { bm = s_; bb = c_; } }
            CMP(h0,1,1) CMP(h0,2,2) CMP(h0,3,3)
            CMP(h0,4,4) CMP(h0,5,5) CMP(h0,6,6) CMP(h0,7,7)
            CMP(h1,0,8) CMP(h1,1,9) CMP(h1,2,10) CMP(h1,3,11)
            CMP(h1,4,12) CMP(h1,5,13) CMP(h1,6,14) CMP(h1,7,15)
#undef CMP
            { float pm = __shfl_xor(bm, 16, 64); int pb = __shfl_xor(bb, 16, 64);
              if (pm < bm || (pm == bm && pb < bb)) { bm = pm; bb = pb; } }
            { float pm = __shfl_xor(bm, 32, 64); int pb = __shfl_xor(bb, 32, 64);
              if (pm < bm || (pm == bm && pb < bb)) { bm = pm; bb = pb; } }
            if (kq == 0) { sidx[i & 1][p_] = bb; atomicAdd(&scnt[bb], 1); }
        }
        LGKM0; SBAR;   // sidx(i) visible for phase-B in iter i+1
    }

    // ---- writeback: D row = M*16+4g+r (cluster), col = bcol ----
    if (useAtomic) {
#define WBK(M, ACC) { \
        { int cl_ = (M)*16 + 4*g + 0; if (cl_ < K) atomicAdd(&out[cl_ * D + bcol], ACC[0]); } \
        { int cl_ = (M)*16 + 4*g + 1; if (cl_ < K) atomicAdd(&out[cl_ * D + bcol], ACC[1]); } \
        { int cl_ = (M)*16 + 4*g + 2; if (cl_ < K) atomicAdd(&out[cl_ * D + bcol], ACC[2]); } \
        { int cl_ = (M)*16 + 4*g + 3; if (cl_ < K) atomicAdd(&out[cl_ * D + bcol], ACC[3]); } }
        WBK(0, bacc0) WBK(1, bacc1) WBK(2, bacc2) WBK(3, bacc3)
#undef WBK
    } else {
        float* pb = partial + (size_t)bid * KD;
#define WBK(M, ACC) { \
        { int cl_ = (M)*16 + 4*g + 0; if (cl_ < K) pb[cl_ * D + bcol] = ACC[0]; } \
        { int cl_ = (M)*16 + 4*g + 1; if (cl_ < K) pb[cl_ * D + bcol] = ACC[1]; } \
        { int cl_ = (M)*16 + 4*g + 2; if (cl_ < K) pb[cl_ * D + bcol] = ACC[2]; } \
        { int cl_ = (M)*16 + 4*g + 3; if (cl_ < K) pb[cl_ * D + bcol] = ACC[3]; } }
        WBK(0, bacc0) WBK(1, bacc1) WBK(2, bacc2) WBK(3, bacc3)
#undef WBK
    }
    __syncthreads();
    for (int k = tid; k < K; k += BLK) atomicAdd(&out[KD + k], (float)scnt[k]);
}

// partial reduction: 8 slices of 64 partials, atomicAdd into zeroed out
__global__ __launch_bounds__(256)
void k_reduce(const float* __restrict__ partial, float* __restrict__ out, int G) {
    const int j  = blockIdx.x * 256 + threadIdx.x;    // < KD
    const int bs = G / 8;
    const int b0 = blockIdx.y * bs;
    float s = 0.f;
    for (int b = b0; b < b0 + bs; ++b) s += partial[(size_t)b * KD + j];
    atomicAdd(&out[j], s);
}

extern "C" void kernel_launch(void* const* d_in, const int* in_sizes, int n_in,
                              void* d_out, int out_size, void* d_ws, size_t ws_size,
                              hipStream_t stream) {
    const float* x = (const float*)d_in[0];
    const float* c = (const float*)d_in[1];
    float* out = (float*)d_out;
    const int N = in_sizes[0] / D;

    float* partial = (float*)d_ws;
    const size_t need = (size_t)GRID * KD * sizeof(float);
    const int useAtomic = (ws_size < need) ? 1 : 0;

    hipMemsetAsync(d_out, 0, (size_t)out_size * sizeof(float), stream);
    k_fused<<<GRID, BLK, 0, stream>>>(x, c, partial, out, N, useAtomic);
    if (!useAtomic) {
        k_reduce<<<dim3(KD / 256, 8), 256, 0, stream>>>(partial, out, GRID);
    }
}